// Round 2
// baseline (831.539 us; speedup 1.0000x reference)
//
#include <hip/hip_runtime.h>

constexpr int kB  = 512;
constexpr int kV  = 6890;
constexpr int kJ  = 24;
constexpr int kD  = kV * 3;   // 20670
constexpr int kNB = 10;
constexpr int kNF = 93;

// ---------------------------------------------------------------------------
// K1: v_shaped[b][d] = dot(shapedirs[d][:], betas[b][:]) + v_template[d]
// block: 256 threads over d, 8 batches per block
// ---------------------------------------------------------------------------
__global__ __launch_bounds__(256) void k1_shape(
    const float* __restrict__ shapedirs, const float* __restrict__ betas,
    const float* __restrict__ v_template, float* __restrict__ out_vshaped) {
  __shared__ float sb[8][kNB];
  int tid = threadIdx.x;
  int b0 = blockIdx.y * 8;
  if (tid < 8 * kNB)
    sb[tid / kNB][tid % kNB] = betas[(b0 + tid / kNB) * kNB + tid % kNB];
  __syncthreads();
  int d = blockIdx.x * 256 + tid;
  if (d >= kD) return;
  float sd[kNB];
#pragma unroll
  for (int k = 0; k < kNB; ++k) sd[k] = shapedirs[(size_t)d * kNB + k];
  float vt = v_template[d];
#pragma unroll
  for (int t = 0; t < 8; ++t) {
    float acc = vt;
#pragma unroll
    for (int k = 0; k < kNB; ++k) acc += sd[k] * sb[t][k];
    out_vshaped[(size_t)(b0 + t) * kD + d] = acc;
  }
}

// ---------------------------------------------------------------------------
// K2: Jp[b][j][k] = sum_v Jreg[j][v] * v_shaped[b][v][k]
// one block per batch; 4 waves x 6 joints, register acc + shuffle reduce
// ---------------------------------------------------------------------------
__global__ __launch_bounds__(256) void k2_jp(
    const float* __restrict__ Jreg, const float* __restrict__ vshaped,
    float* __restrict__ Jp) {
  int b = blockIdx.x;
  int tid = threadIdx.x;
  int wave = tid >> 6, lane = tid & 63;
  int j0 = wave * 6;
  float acc[6][3];
#pragma unroll
  for (int jj = 0; jj < 6; ++jj)
#pragma unroll
    for (int k = 0; k < 3; ++k) acc[jj][k] = 0.f;
  const float* vs = vshaped + (size_t)b * kD;
  for (int v = lane; v < kV; v += 64) {
    float p0 = vs[v * 3 + 0];
    float p1 = vs[v * 3 + 1];
    float p2 = vs[v * 3 + 2];
#pragma unroll
    for (int jj = 0; jj < 6; ++jj) {
      float w = Jreg[(size_t)(j0 + jj) * kV + v];
      acc[jj][0] += w * p0;
      acc[jj][1] += w * p1;
      acc[jj][2] += w * p2;
    }
  }
#pragma unroll
  for (int jj = 0; jj < 6; ++jj)
#pragma unroll
    for (int k = 0; k < 3; ++k)
      for (int off = 32; off > 0; off >>= 1)
        acc[jj][k] += __shfl_down(acc[jj][k], off, 64);
  if (lane == 0) {
#pragma unroll
    for (int jj = 0; jj < 6; ++jj)
#pragma unroll
      for (int k = 0; k < 3; ++k)
        Jp[b * 72 + (j0 + jj) * 3 + k] = acc[jj][k];
  }
}

// ---------------------------------------------------------------------------
// K3: per-batch pose features (transposed [f][b]), Rodrigues, kinematic chain
// (level-parallel over tree depth), G_skin, J_transformed.
// one block (1 wave) per batch; threads j = 0..23 active
// ---------------------------------------------------------------------------
__global__ __launch_bounds__(64) void k3_chain(
    const float* __restrict__ pose, const float* __restrict__ betas,
    const float* __restrict__ trans, const float* __restrict__ Jp_g,
    float* __restrict__ pfT, float* __restrict__ Gskin,
    float* __restrict__ out_Jt) {
  const int parent[24] = {-1, 0, 0, 0, 1, 2, 3, 4, 5, 6, 7, 8,
                          9, 9, 9, 12, 13, 14, 16, 17, 18, 19, 20, 21};
  const int depth[24] = {0, 1, 1, 1, 2, 2, 2, 3, 3, 3, 4, 4,
                         4, 4, 4, 5, 5, 5, 6, 6, 7, 7, 8, 8};
  int b = blockIdx.x;
  int j = threadIdx.x;
  __shared__ float G[24][12];
  float R[9];
  float tl[3];
  if (j < 24) {
    float t0 = pose[b * 72 + 3 * j + 0];
    float t1 = pose[b * 72 + 3 * j + 1];
    float t2 = pose[b * 72 + 3 * j + 2];
    float a0 = t0 + 1e-8f, a1 = t1 + 1e-8f, a2 = t2 + 1e-8f;
    float angle = sqrtf(a0 * a0 + a1 * a1 + a2 * a2);
    float inv = 1.0f / angle;
    float h = 0.5f * angle;
    float c = cosf(h), s = sinf(h);
    float x = s * t0 * inv, y = s * t1 * inv, z = s * t2 * inv, w = c;
    if (j >= 1) {
      int f = 4 * (j - 1);
      pfT[(size_t)(f + 0) * kB + b] = x;
      pfT[(size_t)(f + 1) * kB + b] = y;
      pfT[(size_t)(f + 2) * kB + b] = z;
      pfT[(size_t)(f + 3) * kB + b] = c - 1.0f;
    } else {
      pfT[(size_t)92 * kB + b] = betas[b * kNB + 1];
    }
    float xx = x * x, yy = y * y, zz = z * z;
    float wx = w * x, wy = w * y, wz = w * z;
    float xy = x * y, xz = x * z, yz = y * z;
    R[0] = 1.f - 2.f * (yy + zz); R[1] = 2.f * (xy - wz); R[2] = 2.f * (xz + wy);
    R[3] = 2.f * (xy + wz); R[4] = 1.f - 2.f * (xx + zz); R[5] = 2.f * (yz - wx);
    R[6] = 2.f * (xz - wy); R[7] = 2.f * (yz + wx); R[8] = 1.f - 2.f * (xx + yy);
    int p = parent[j];
#pragma unroll
    for (int k = 0; k < 3; ++k) {
      float jv = Jp_g[b * 72 + j * 3 + k];
      tl[k] = (p >= 0) ? (jv - Jp_g[b * 72 + p * 3 + k]) : jv;
    }
    if (j == 0) {
#pragma unroll
      for (int r = 0; r < 3; ++r) {
        G[0][r * 4 + 0] = R[r * 3 + 0];
        G[0][r * 4 + 1] = R[r * 3 + 1];
        G[0][r * 4 + 2] = R[r * 3 + 2];
        G[0][r * 4 + 3] = tl[r];
      }
    }
  }
  __syncthreads();
  for (int lev = 1; lev <= 8; ++lev) {
    if (j < 24 && depth[j] == lev) {
      int p = parent[j];
      float nG[12];
#pragma unroll
      for (int r = 0; r < 3; ++r) {
        float g0 = G[p][r * 4 + 0], g1 = G[p][r * 4 + 1];
        float g2 = G[p][r * 4 + 2], g3 = G[p][r * 4 + 3];
        nG[r * 4 + 0] = g0 * R[0] + g1 * R[3] + g2 * R[6];
        nG[r * 4 + 1] = g0 * R[1] + g1 * R[4] + g2 * R[7];
        nG[r * 4 + 2] = g0 * R[2] + g1 * R[5] + g2 * R[8];
        nG[r * 4 + 3] = g0 * tl[0] + g1 * tl[1] + g2 * tl[2] + g3;
      }
#pragma unroll
      for (int e = 0; e < 12; ++e) G[j][e] = nG[e];
    }
    __syncthreads();
  }
  if (j < 24) {
    float tr[3];
#pragma unroll
    for (int k = 0; k < 3; ++k) tr[k] = trans[b * 3 + k];
#pragma unroll
    for (int k = 0; k < 3; ++k)
      out_Jt[b * 72 + j * 3 + k] = G[j][k * 4 + 3] + tr[k];
    float jp0 = Jp_g[b * 72 + j * 3 + 0];
    float jp1 = Jp_g[b * 72 + j * 3 + 1];
    float jp2 = Jp_g[b * 72 + j * 3 + 2];
    float* gs = Gskin + b * 288 + j * 12;
#pragma unroll
    for (int r = 0; r < 3; ++r) {
      float t = G[j][r * 4 + 0] * jp0 + G[j][r * 4 + 1] * jp1 + G[j][r * 4 + 2] * jp2;
      gs[r * 4 + 0] = G[j][r * 4 + 0];
      gs[r * 4 + 1] = G[j][r * 4 + 1];
      gs[r * 4 + 2] = G[j][r * 4 + 2];
      gs[r * 4 + 3] = G[j][r * 4 + 3] - t;
    }
  }
}

// ---------------------------------------------------------------------------
// K4: v_posed[b][d] = v_shaped[b][d] + dot(posedirs[d][:], pose_feat[b][:])
// thread: 2 d-rows x 16 batches; pose_feat read uniform (scalar loads)
// ---------------------------------------------------------------------------
__global__ __launch_bounds__(256) void k4_posed(
    const float* __restrict__ posedirs, const float* __restrict__ pfT,
    const float* __restrict__ vshaped, float* __restrict__ out_vposed) {
  int tid = threadIdx.x;
  int b0 = blockIdx.y * 16;
  int d0 = blockIdx.x * 512 + tid;
  int d1 = d0 + 256;
  bool a0 = d0 < kD, a1 = d1 < kD;
  const float* p0 = posedirs + (size_t)d0 * kNF;
  const float* p1 = posedirs + (size_t)d1 * kNF;
  float A0[16], A1[16];
#pragma unroll
  for (int t = 0; t < 16; ++t) { A0[t] = 0.f; A1[t] = 0.f; }
  for (int f = 0; f < kNF; ++f) {
    float x0 = a0 ? p0[f] : 0.f;
    float x1 = a1 ? p1[f] : 0.f;
    const float* q = pfT + (size_t)f * kB + b0;  // wave-uniform
#pragma unroll
    for (int t = 0; t < 16; ++t) {
      float pv = q[t];
      A0[t] += x0 * pv;
      A1[t] += x1 * pv;
    }
  }
#pragma unroll
  for (int t = 0; t < 16; ++t) {
    if (a0) {
      size_t idx = (size_t)(b0 + t) * kD + d0;
      out_vposed[idx] = A0[t] + vshaped[idx];
    }
    if (a1) {
      size_t idx = (size_t)(b0 + t) * kD + d1;
      out_vposed[idx] = A1[t] + vshaped[idx];
    }
  }
}

// ---------------------------------------------------------------------------
// K5: LBS skinning. one block per (v-tile, b); G_skin read wave-uniform.
// thread: 2 vertices
// ---------------------------------------------------------------------------
__global__ __launch_bounds__(256) void k5_skin(
    const float* __restrict__ weights, const float* __restrict__ Gskin,
    const float* __restrict__ trans, const float* __restrict__ vposed,
    float* __restrict__ out_v) {
  int b = blockIdx.y;
  int tid = threadIdx.x;
  const float* Gb = Gskin + (size_t)b * 288;
  float tr0 = trans[b * 3 + 0];
  float tr1 = trans[b * 3 + 1];
  float tr2 = trans[b * 3 + 2];
  int v0 = blockIdx.x * 512 + tid;
  int v1 = v0 + 256;
  bool a0 = v0 < kV, a1 = v1 < kV;
  float T0[12], T1[12];
#pragma unroll
  for (int e = 0; e < 12; ++e) { T0[e] = 0.f; T1[e] = 0.f; }
  for (int j = 0; j < kJ; ++j) {
    float w0 = a0 ? weights[(size_t)v0 * kJ + j] : 0.f;
    float w1 = a1 ? weights[(size_t)v1 * kJ + j] : 0.f;
#pragma unroll
    for (int e = 0; e < 12; ++e) {
      float g = Gb[j * 12 + e];  // wave-uniform -> scalar load
      T0[e] += w0 * g;
      T1[e] += w1 * g;
    }
  }
  if (a0) {
    size_t base = (size_t)b * kD + (size_t)v0 * 3;
    float q0 = vposed[base + 0];
    float q1 = vposed[base + 1];
    float q2 = vposed[base + 2];
    out_v[base + 0] = T0[0] * q0 + T0[1] * q1 + T0[2] * q2 + T0[3] + tr0;
    out_v[base + 1] = T0[4] * q0 + T0[5] * q1 + T0[6] * q2 + T0[7] + tr1;
    out_v[base + 2] = T0[8] * q0 + T0[9] * q1 + T0[10] * q2 + T0[11] + tr2;
  }
  if (a1) {
    size_t base = (size_t)b * kD + (size_t)v1 * 3;
    float q0 = vposed[base + 0];
    float q1 = vposed[base + 1];
    float q2 = vposed[base + 2];
    out_v[base + 0] = T1[0] * q0 + T1[1] * q1 + T1[2] * q2 + T1[3] + tr0;
    out_v[base + 1] = T1[4] * q0 + T1[5] * q1 + T1[6] * q2 + T1[7] + tr1;
    out_v[base + 2] = T1[8] * q0 + T1[9] * q1 + T1[10] * q2 + T1[11] + tr2;
  }
}

// ---------------------------------------------------------------------------
extern "C" void kernel_launch(void* const* d_in, const int* in_sizes, int n_in,
                              void* d_out, int out_size, void* d_ws,
                              size_t ws_size, hipStream_t stream) {
  const float* pose       = (const float*)d_in[0];
  const float* betas      = (const float*)d_in[1];
  const float* trans      = (const float*)d_in[2];
  const float* v_template = (const float*)d_in[3];
  const float* shapedirs  = (const float*)d_in[4];
  const float* posedirs   = (const float*)d_in[5];
  const float* Jreg       = (const float*)d_in[6];
  const float* weights    = (const float*)d_in[7];

  float* out = (float*)d_out;
  float* out_v       = out;
  float* out_vposed  = out + (size_t)kB * kD;
  float* out_vshaped = out + 2 * (size_t)kB * kD;
  float* out_Jt      = out + 3 * (size_t)kB * kD;

  float* wsf   = (float*)d_ws;
  float* Jp    = wsf;                 // kB*72
  float* pfT   = Jp + kB * 72;        // kNF*kB (transposed [f][b])
  float* Gskin = pfT + kNF * kB;      // kB*288

  hipLaunchKernelGGL(k1_shape, dim3((kD + 255) / 256, kB / 8), dim3(256), 0,
                     stream, shapedirs, betas, v_template, out_vshaped);
  hipLaunchKernelGGL(k2_jp, dim3(kB), dim3(256), 0, stream, Jreg, out_vshaped,
                     Jp);
  hipLaunchKernelGGL(k3_chain, dim3(kB), dim3(64), 0, stream, pose, betas,
                     trans, Jp, pfT, Gskin, out_Jt);
  hipLaunchKernelGGL(k4_posed, dim3((kD + 511) / 512, kB / 16), dim3(256), 0,
                     stream, posedirs, pfT, out_vshaped, out_vposed);
  hipLaunchKernelGGL(k5_skin, dim3((kV + 511) / 512, kB), dim3(256), 0, stream,
                     weights, Gskin, trans, out_vposed, out_v);
}

// Round 3
// 415.312 us; speedup vs baseline: 2.0022x; 2.0022x over previous
//
#include <hip/hip_runtime.h>

constexpr int kB  = 512;
constexpr int kV  = 6890;
constexpr int kJ  = 24;
constexpr int kD  = kV * 3;   // 20670
constexpr int kNB = 10;
constexpr int kNF = 93;

// ---------------------------------------------------------------------------
// K0: per-batch pose prep. Computes quaternion features -> pfT (transposed
// [f][b]), Rodrigues R -> Rg, and zeroes Jp for k2's atomics.
// grid(kB), block(128)
// ---------------------------------------------------------------------------
__global__ __launch_bounds__(128) void k0_prep(
    const float* __restrict__ pose, const float* __restrict__ betas,
    float* __restrict__ pfT, float* __restrict__ Rg, float* __restrict__ Jp) {
  int b = blockIdx.x;
  int t = threadIdx.x;
  if (t < 72) Jp[b * 72 + t] = 0.f;
  if (t < 24) {
    int j = t;
    float t0 = pose[b * 72 + 3 * j + 0];
    float t1 = pose[b * 72 + 3 * j + 1];
    float t2 = pose[b * 72 + 3 * j + 2];
    float a0 = t0 + 1e-8f, a1 = t1 + 1e-8f, a2 = t2 + 1e-8f;
    float angle = sqrtf(a0 * a0 + a1 * a1 + a2 * a2);
    float inv = 1.0f / angle;
    float h = 0.5f * angle;
    float c = cosf(h), s = sinf(h);
    float x = s * t0 * inv, y = s * t1 * inv, z = s * t2 * inv, w = c;
    if (j >= 1) {
      int f = 4 * (j - 1);
      pfT[(size_t)(f + 0) * kB + b] = x;
      pfT[(size_t)(f + 1) * kB + b] = y;
      pfT[(size_t)(f + 2) * kB + b] = z;
      pfT[(size_t)(f + 3) * kB + b] = c - 1.0f;
    } else {
      pfT[(size_t)92 * kB + b] = betas[b * kNB + 1];
    }
    float xx = x * x, yy = y * y, zz = z * z;
    float wx = w * x, wy = w * y, wz = w * z;
    float xy = x * y, xz = x * z, yz = y * z;
    float* R = Rg + (size_t)b * 216 + j * 9;
    R[0] = 1.f - 2.f * (yy + zz); R[1] = 2.f * (xy - wz); R[2] = 2.f * (xz + wy);
    R[3] = 2.f * (xy + wz); R[4] = 1.f - 2.f * (xx + zz); R[5] = 2.f * (yz - wx);
    R[6] = 2.f * (xz - wy); R[7] = 2.f * (yz + wx); R[8] = 1.f - 2.f * (xx + yy);
  }
}

// ---------------------------------------------------------------------------
// K14: fused shape+pose blend. Thread owns one d-row; shapedirs row (10) and
// posedirs row (93) live in registers; loops 64 batches with wave-uniform
// scalar loads of betas/pfT. Writes v_shaped and v_posed coalesced.
// grid(81, 8), block(256)
// ---------------------------------------------------------------------------
__global__ __launch_bounds__(256) void k14_fused(
    const float* __restrict__ shapedirs, const float* __restrict__ posedirs,
    const float* __restrict__ v_template, const float* __restrict__ betas,
    const float* __restrict__ pfT, float* __restrict__ out_vshaped,
    float* __restrict__ out_vposed) {
  int tid = threadIdx.x;
  int d = blockIdx.x * 256 + tid;
  bool active = d < kD;
  int dl = active ? d : (kD - 1);  // clamp for loads
  float sd[kNB], pd[kNF];
#pragma unroll
  for (int k = 0; k < kNB; ++k) sd[k] = shapedirs[(size_t)dl * kNB + k];
#pragma unroll
  for (int f = 0; f < kNF; ++f) pd[f] = posedirs[(size_t)dl * kNF + f];
  float vt = v_template[dl];
  int b0 = blockIdx.y * 64;
#pragma unroll 1
  for (int bc = 0; bc < 8; ++bc) {
    int bb = b0 + bc * 8;
    float as[8], ap[8];
#pragma unroll
    for (int t = 0; t < 8; ++t) {
      float a = vt;
#pragma unroll
      for (int k = 0; k < kNB; ++k) a += sd[k] * betas[(size_t)(bb + t) * kNB + k];
      as[t] = a;
      ap[t] = a;
    }
#pragma unroll
    for (int f = 0; f < kNF; ++f) {
      float pdf = pd[f];
      const float* q = pfT + (size_t)f * kB + bb;  // wave-uniform
#pragma unroll
      for (int t = 0; t < 8; ++t) ap[t] += pdf * q[t];
    }
    if (active) {
#pragma unroll
      for (int t = 0; t < 8; ++t) {
        size_t idx = (size_t)(bb + t) * kD + d;
        out_vshaped[idx] = as[t];
        out_vposed[idx] = ap[t];
      }
    }
  }
}

// ---------------------------------------------------------------------------
// K2: Jp[b][j][k] += sum_{v in chunk} Jreg[j][v] * v_shaped[b][v][k]
// grid(8 v-chunks, 32 b-chunks), block 256 = 4 waves x 6 joints.
// Jreg slice stays cache-resident across the 16 batches; atomic finish.
// ---------------------------------------------------------------------------
__global__ __launch_bounds__(256) void k2_jp(
    const float* __restrict__ Jreg, const float* __restrict__ vshaped,
    float* __restrict__ Jp) {
  int tid = threadIdx.x;
  int wave = tid >> 6, lane = tid & 63;
  int j0 = wave * 6;
  const int vchunk = (kV + 7) / 8;  // 862
  int vstart = blockIdx.x * vchunk;
  int vend = min(kV, vstart + vchunk);
  int b0 = blockIdx.y * 16;
#pragma unroll 1
  for (int bi = 0; bi < 16; ++bi) {
    int b = b0 + bi;
    const float* vs = vshaped + (size_t)b * kD;
    float acc[6][3];
#pragma unroll
    for (int jj = 0; jj < 6; ++jj)
#pragma unroll
      for (int k = 0; k < 3; ++k) acc[jj][k] = 0.f;
    for (int v = vstart + lane; v < vend; v += 64) {
      float p0 = vs[v * 3 + 0];
      float p1 = vs[v * 3 + 1];
      float p2 = vs[v * 3 + 2];
#pragma unroll
      for (int jj = 0; jj < 6; ++jj) {
        float w = Jreg[(size_t)(j0 + jj) * kV + v];
        acc[jj][0] += w * p0;
        acc[jj][1] += w * p1;
        acc[jj][2] += w * p2;
      }
    }
#pragma unroll
    for (int jj = 0; jj < 6; ++jj)
#pragma unroll
      for (int k = 0; k < 3; ++k)
#pragma unroll
        for (int off = 32; off > 0; off >>= 1)
          acc[jj][k] += __shfl_down(acc[jj][k], off, 64);
    if (lane == 0) {
#pragma unroll
      for (int jj = 0; jj < 6; ++jj)
#pragma unroll
        for (int k = 0; k < 3; ++k)
          atomicAdd(&Jp[b * 72 + (j0 + jj) * 3 + k], acc[jj][k]);
    }
  }
}

// ---------------------------------------------------------------------------
// K3: kinematic chain (level-parallel), G_skin, J_transformed.
// one block (1 wave) per batch; threads j = 0..23 active. R precomputed (k0).
// ---------------------------------------------------------------------------
__global__ __launch_bounds__(64) void k3_chain(
    const float* __restrict__ trans, const float* __restrict__ Jp_g,
    const float* __restrict__ Rg, float* __restrict__ Gskin,
    float* __restrict__ out_Jt) {
  const int parent[24] = {-1, 0, 0, 0, 1, 2, 3, 4, 5, 6, 7, 8,
                          9, 9, 9, 12, 13, 14, 16, 17, 18, 19, 20, 21};
  const int depth[24] = {0, 1, 1, 1, 2, 2, 2, 3, 3, 3, 4, 4,
                         4, 4, 4, 5, 5, 5, 6, 6, 7, 7, 8, 8};
  int b = blockIdx.x;
  int j = threadIdx.x;
  __shared__ float G[24][12];
  float R[9];
  float tl[3];
  if (j < 24) {
#pragma unroll
    for (int e = 0; e < 9; ++e) R[e] = Rg[(size_t)b * 216 + j * 9 + e];
    int p = parent[j];
#pragma unroll
    for (int k = 0; k < 3; ++k) {
      float jv = Jp_g[b * 72 + j * 3 + k];
      tl[k] = (p >= 0) ? (jv - Jp_g[b * 72 + p * 3 + k]) : jv;
    }
    if (j == 0) {
#pragma unroll
      for (int r = 0; r < 3; ++r) {
        G[0][r * 4 + 0] = R[r * 3 + 0];
        G[0][r * 4 + 1] = R[r * 3 + 1];
        G[0][r * 4 + 2] = R[r * 3 + 2];
        G[0][r * 4 + 3] = tl[r];
      }
    }
  }
  __syncthreads();
  for (int lev = 1; lev <= 8; ++lev) {
    if (j < 24 && depth[j] == lev) {
      int p = parent[j];
      float nG[12];
#pragma unroll
      for (int r = 0; r < 3; ++r) {
        float g0 = G[p][r * 4 + 0], g1 = G[p][r * 4 + 1];
        float g2 = G[p][r * 4 + 2], g3 = G[p][r * 4 + 3];
        nG[r * 4 + 0] = g0 * R[0] + g1 * R[3] + g2 * R[6];
        nG[r * 4 + 1] = g0 * R[1] + g1 * R[4] + g2 * R[7];
        nG[r * 4 + 2] = g0 * R[2] + g1 * R[5] + g2 * R[8];
        nG[r * 4 + 3] = g0 * tl[0] + g1 * tl[1] + g2 * tl[2] + g3;
      }
#pragma unroll
      for (int e = 0; e < 12; ++e) G[j][e] = nG[e];
    }
    __syncthreads();
  }
  if (j < 24) {
    float tr[3];
#pragma unroll
    for (int k = 0; k < 3; ++k) tr[k] = trans[b * 3 + k];
#pragma unroll
    for (int k = 0; k < 3; ++k)
      out_Jt[b * 72 + j * 3 + k] = G[j][k * 4 + 3] + tr[k];
    float jp0 = Jp_g[b * 72 + j * 3 + 0];
    float jp1 = Jp_g[b * 72 + j * 3 + 1];
    float jp2 = Jp_g[b * 72 + j * 3 + 2];
    float* gs = Gskin + b * 288 + j * 12;
#pragma unroll
    for (int r = 0; r < 3; ++r) {
      float t = G[j][r * 4 + 0] * jp0 + G[j][r * 4 + 1] * jp1 + G[j][r * 4 + 2] * jp2;
      gs[r * 4 + 0] = G[j][r * 4 + 0];
      gs[r * 4 + 1] = G[j][r * 4 + 1];
      gs[r * 4 + 2] = G[j][r * 4 + 2];
      gs[r * 4 + 3] = G[j][r * 4 + 3] - t;
    }
  }
}

// ---------------------------------------------------------------------------
// K5: LBS skinning. Block owns a 256-vertex tile; weights row (24) lives in
// registers; loops 32 batches with wave-uniform scalar loads of G_skin.
// grid(27, 16), block(256)
// ---------------------------------------------------------------------------
__global__ __launch_bounds__(256) void k5_skin(
    const float* __restrict__ weights, const float* __restrict__ Gskin,
    const float* __restrict__ trans, const float* __restrict__ vposed,
    float* __restrict__ out_v) {
  int tid = threadIdx.x;
  int v = blockIdx.x * 256 + tid;
  bool active = v < kV;
  int vl = active ? v : (kV - 1);
  float w[kJ];
#pragma unroll
  for (int j = 0; j < kJ; ++j) w[j] = weights[(size_t)vl * kJ + j];
  int b0 = blockIdx.y * 32;
#pragma unroll 1
  for (int bi = 0; bi < 32; ++bi) {
    int b = b0 + bi;
    const float* Gb = Gskin + (size_t)b * 288;  // wave-uniform
    float T[12];
#pragma unroll
    for (int e = 0; e < 12; ++e) T[e] = 0.f;
#pragma unroll
    for (int j = 0; j < kJ; ++j) {
      float wj = w[j];
#pragma unroll
      for (int e = 0; e < 12; ++e) T[e] += wj * Gb[j * 12 + e];
    }
    float tr0 = trans[b * 3 + 0];
    float tr1 = trans[b * 3 + 1];
    float tr2 = trans[b * 3 + 2];
    size_t base = (size_t)b * kD + (size_t)vl * 3;
    float q0 = vposed[base + 0];
    float q1 = vposed[base + 1];
    float q2 = vposed[base + 2];
    if (active) {
      out_v[base + 0] = T[0] * q0 + T[1] * q1 + T[2] * q2 + T[3] + tr0;
      out_v[base + 1] = T[4] * q0 + T[5] * q1 + T[6] * q2 + T[7] + tr1;
      out_v[base + 2] = T[8] * q0 + T[9] * q1 + T[10] * q2 + T[11] + tr2;
    }
  }
}

// ---------------------------------------------------------------------------
extern "C" void kernel_launch(void* const* d_in, const int* in_sizes, int n_in,
                              void* d_out, int out_size, void* d_ws,
                              size_t ws_size, hipStream_t stream) {
  const float* pose       = (const float*)d_in[0];
  const float* betas      = (const float*)d_in[1];
  const float* trans      = (const float*)d_in[2];
  const float* v_template = (const float*)d_in[3];
  const float* shapedirs  = (const float*)d_in[4];
  const float* posedirs   = (const float*)d_in[5];
  const float* Jreg       = (const float*)d_in[6];
  const float* weights    = (const float*)d_in[7];

  float* out = (float*)d_out;
  float* out_v       = out;
  float* out_vposed  = out + (size_t)kB * kD;
  float* out_vshaped = out + 2 * (size_t)kB * kD;
  float* out_Jt      = out + 3 * (size_t)kB * kD;

  float* wsf   = (float*)d_ws;
  float* Jp    = wsf;                  // kB*72
  float* pfT   = Jp + kB * 72;         // kNF*kB
  float* Gskin = pfT + kNF * kB;       // kB*288
  float* Rg    = Gskin + kB * 288;     // kB*216

  hipLaunchKernelGGL(k0_prep, dim3(kB), dim3(128), 0, stream, pose, betas,
                     pfT, Rg, Jp);
  hipLaunchKernelGGL(k14_fused, dim3((kD + 255) / 256, 8), dim3(256), 0,
                     stream, shapedirs, posedirs, v_template, betas, pfT,
                     out_vshaped, out_vposed);
  hipLaunchKernelGGL(k2_jp, dim3(8, 32), dim3(256), 0, stream, Jreg,
                     out_vshaped, Jp);
  hipLaunchKernelGGL(k3_chain, dim3(kB), dim3(64), 0, stream, trans, Jp, Rg,
                     Gskin, out_Jt);
  hipLaunchKernelGGL(k5_skin, dim3((kV + 255) / 256, 16), dim3(256), 0, stream,
                     weights, Gskin, trans, out_vposed, out_v);
}

// Round 4
// 265.531 us; speedup vs baseline: 3.1316x; 1.5641x over previous
//
#include <hip/hip_runtime.h>

constexpr int kB  = 512;
constexpr int kV  = 6890;
constexpr int kJ  = 24;
constexpr int kD  = kV * 3;   // 20670
constexpr int kNB = 10;
constexpr int kNF = 93;

// ---------------------------------------------------------------------------
// KA: batch-independent joint-regressor folding.
// JS[j][k][nb] = sum_v Jreg[j][v] * shapedirs[(v*3+k)*10+nb]
// JT[j][k]     = sum_v Jreg[j][v] * v_template[v*3+k]
// grid(72): one block per (j,k). block(256), wave butterfly + LDS reduce.
// ---------------------------------------------------------------------------
__global__ __launch_bounds__(256) void kA_js(
    const float* __restrict__ Jreg, const float* __restrict__ shapedirs,
    const float* __restrict__ v_template, float* __restrict__ js,
    float* __restrict__ jt) {
  int jk = blockIdx.x;
  int j = jk / 3, k = jk % 3;
  int tid = threadIdx.x;
  float acc[kNB];
  float accT = 0.f;
#pragma unroll
  for (int nb = 0; nb < kNB; ++nb) acc[nb] = 0.f;
  for (int v = tid; v < kV; v += 256) {
    float w = Jreg[(size_t)j * kV + v];
    const float* srow = shapedirs + (size_t)(v * 3 + k) * kNB;
    accT += w * v_template[v * 3 + k];
#pragma unroll
    for (int nb = 0; nb < kNB; ++nb) acc[nb] += w * srow[nb];
  }
#pragma unroll
  for (int nb = 0; nb < kNB; ++nb)
#pragma unroll
    for (int off = 32; off > 0; off >>= 1)
      acc[nb] += __shfl_down(acc[nb], off, 64);
#pragma unroll
  for (int off = 32; off > 0; off >>= 1) accT += __shfl_down(accT, off, 64);
  __shared__ float red[4][11];
  int wave = tid >> 6, lane = tid & 63;
  if (lane == 0) {
#pragma unroll
    for (int nb = 0; nb < kNB; ++nb) red[wave][nb] = acc[nb];
    red[wave][10] = accT;
  }
  __syncthreads();
  if (tid == 0) {
#pragma unroll
    for (int nb = 0; nb < kNB; ++nb)
      js[jk * kNB + nb] = red[0][nb] + red[1][nb] + red[2][nb] + red[3][nb];
    jt[jk] = red[0][10] + red[1][10] + red[2][10] + red[3][10];
  }
}

// ---------------------------------------------------------------------------
// KC: per-batch everything-small. Quat features -> pfT ([f][b] transposed),
// Rodrigues R (regs), Jp = JT + JS*betas (LDS), kinematic chain by tree
// level, G_skin, J_transformed. grid(kB), block(64) = 1 wave.
// ---------------------------------------------------------------------------
__global__ __launch_bounds__(64) void kC_batch(
    const float* __restrict__ pose, const float* __restrict__ betas,
    const float* __restrict__ trans, const float* __restrict__ js,
    const float* __restrict__ jt, float* __restrict__ pfT,
    float* __restrict__ Gskin, float* __restrict__ out_Jt) {
  const int parent[24] = {-1, 0, 0, 0, 1, 2, 3, 4, 5, 6, 7, 8,
                          9, 9, 9, 12, 13, 14, 16, 17, 18, 19, 20, 21};
  const int depth[24] = {0, 1, 1, 1, 2, 2, 2, 3, 3, 3, 4, 4,
                         4, 4, 4, 5, 5, 5, 6, 6, 7, 7, 8, 8};
  int b = blockIdx.x;
  int j = threadIdx.x;
  __shared__ float G[24][12];
  __shared__ float Jp_s[24][3];
  float R[9];
  if (j < 24) {
    float t0 = pose[b * 72 + 3 * j + 0];
    float t1 = pose[b * 72 + 3 * j + 1];
    float t2 = pose[b * 72 + 3 * j + 2];
    float a0 = t0 + 1e-8f, a1 = t1 + 1e-8f, a2 = t2 + 1e-8f;
    float angle = sqrtf(a0 * a0 + a1 * a1 + a2 * a2);
    float inv = 1.0f / angle;
    float h = 0.5f * angle;
    float c = cosf(h), s = sinf(h);
    float x = s * t0 * inv, y = s * t1 * inv, z = s * t2 * inv, w = c;
    if (j >= 1) {
      int f = 4 * (j - 1);
      pfT[(size_t)(f + 0) * kB + b] = x;
      pfT[(size_t)(f + 1) * kB + b] = y;
      pfT[(size_t)(f + 2) * kB + b] = z;
      pfT[(size_t)(f + 3) * kB + b] = c - 1.0f;
    } else {
      pfT[(size_t)92 * kB + b] = betas[b * kNB + 1];
    }
    float xx = x * x, yy = y * y, zz = z * z;
    float wx = w * x, wy = w * y, wz = w * z;
    float xy = x * y, xz = x * z, yz = y * z;
    R[0] = 1.f - 2.f * (yy + zz); R[1] = 2.f * (xy - wz); R[2] = 2.f * (xz + wy);
    R[3] = 2.f * (xy + wz); R[4] = 1.f - 2.f * (xx + zz); R[5] = 2.f * (yz - wx);
    R[6] = 2.f * (xz - wy); R[7] = 2.f * (yz + wx); R[8] = 1.f - 2.f * (xx + yy);
    float bet[kNB];
#pragma unroll
    for (int nb = 0; nb < kNB; ++nb) bet[nb] = betas[b * kNB + nb];
#pragma unroll
    for (int k = 0; k < 3; ++k) {
      float a = jt[j * 3 + k];
      const float* jr = js + (size_t)(j * 3 + k) * kNB;
#pragma unroll
      for (int nb = 0; nb < kNB; ++nb) a += jr[nb] * bet[nb];
      Jp_s[j][k] = a;
    }
  }
  __syncthreads();
  float tl[3];
  if (j < 24) {
    int p = parent[j];
#pragma unroll
    for (int k = 0; k < 3; ++k)
      tl[k] = (p >= 0) ? (Jp_s[j][k] - Jp_s[p][k]) : Jp_s[j][k];
    if (j == 0) {
#pragma unroll
      for (int r = 0; r < 3; ++r) {
        G[0][r * 4 + 0] = R[r * 3 + 0];
        G[0][r * 4 + 1] = R[r * 3 + 1];
        G[0][r * 4 + 2] = R[r * 3 + 2];
        G[0][r * 4 + 3] = tl[r];
      }
    }
  }
  __syncthreads();
  for (int lev = 1; lev <= 8; ++lev) {
    if (j < 24 && depth[j] == lev) {
      int p = parent[j];
      float nG[12];
#pragma unroll
      for (int r = 0; r < 3; ++r) {
        float g0 = G[p][r * 4 + 0], g1 = G[p][r * 4 + 1];
        float g2 = G[p][r * 4 + 2], g3 = G[p][r * 4 + 3];
        nG[r * 4 + 0] = g0 * R[0] + g1 * R[3] + g2 * R[6];
        nG[r * 4 + 1] = g0 * R[1] + g1 * R[4] + g2 * R[7];
        nG[r * 4 + 2] = g0 * R[2] + g1 * R[5] + g2 * R[8];
        nG[r * 4 + 3] = g0 * tl[0] + g1 * tl[1] + g2 * tl[2] + g3;
      }
#pragma unroll
      for (int e = 0; e < 12; ++e) G[j][e] = nG[e];
    }
    __syncthreads();
  }
  if (j < 24) {
    float tr[3];
#pragma unroll
    for (int k = 0; k < 3; ++k) tr[k] = trans[b * 3 + k];
#pragma unroll
    for (int k = 0; k < 3; ++k)
      out_Jt[b * 72 + j * 3 + k] = G[j][k * 4 + 3] + tr[k];
    float jp0 = Jp_s[j][0], jp1 = Jp_s[j][1], jp2 = Jp_s[j][2];
    float* gs = Gskin + b * 288 + j * 12;
#pragma unroll
    for (int r = 0; r < 3; ++r) {
      float t = G[j][r * 4 + 0] * jp0 + G[j][r * 4 + 1] * jp1 + G[j][r * 4 + 2] * jp2;
      gs[r * 4 + 0] = G[j][r * 4 + 0];
      gs[r * 4 + 1] = G[j][r * 4 + 1];
      gs[r * 4 + 2] = G[j][r * 4 + 2];
      gs[r * 4 + 3] = G[j][r * 4 + 3] - t;
    }
  }
}

// ---------------------------------------------------------------------------
// K14: fused shape+pose blend. Thread owns one d-row; dirs rows in registers;
// loops 32 batches with wave-uniform scalar loads of betas/pfT.
// grid(81, 16), block(256)
// ---------------------------------------------------------------------------
__global__ __launch_bounds__(256) void k14_fused(
    const float* __restrict__ shapedirs, const float* __restrict__ posedirs,
    const float* __restrict__ v_template, const float* __restrict__ betas,
    const float* __restrict__ pfT, float* __restrict__ out_vshaped,
    float* __restrict__ out_vposed) {
  int tid = threadIdx.x;
  int d = blockIdx.x * 256 + tid;
  bool active = d < kD;
  int dl = active ? d : (kD - 1);  // clamp for loads
  float sd[kNB], pd[kNF];
#pragma unroll
  for (int k = 0; k < kNB; ++k) sd[k] = shapedirs[(size_t)dl * kNB + k];
#pragma unroll
  for (int f = 0; f < kNF; ++f) pd[f] = posedirs[(size_t)dl * kNF + f];
  float vt = v_template[dl];
  int b0 = blockIdx.y * 32;
#pragma unroll 1
  for (int bc = 0; bc < 4; ++bc) {
    int bb = b0 + bc * 8;
    float as[8], ap[8];
#pragma unroll
    for (int t = 0; t < 8; ++t) {
      float a = vt;
#pragma unroll
      for (int k = 0; k < kNB; ++k) a += sd[k] * betas[(size_t)(bb + t) * kNB + k];
      as[t] = a;
      ap[t] = a;
    }
#pragma unroll
    for (int f = 0; f < kNF; ++f) {
      float pdf = pd[f];
      const float* q = pfT + (size_t)f * kB + bb;  // wave-uniform
#pragma unroll
      for (int t = 0; t < 8; ++t) ap[t] += pdf * q[t];
    }
    if (active) {
#pragma unroll
      for (int t = 0; t < 8; ++t) {
        size_t idx = (size_t)(bb + t) * kD + d;
        out_vshaped[idx] = as[t];
        out_vposed[idx] = ap[t];
      }
    }
  }
}

// ---------------------------------------------------------------------------
// K5: LBS skinning. Block owns a 256-vertex tile; weights row in registers;
// loops 8 batches with wave-uniform scalar loads of G_skin.
// grid(27, 64), block(256)
// ---------------------------------------------------------------------------
__global__ __launch_bounds__(256) void k5_skin(
    const float* __restrict__ weights, const float* __restrict__ Gskin,
    const float* __restrict__ trans, const float* __restrict__ vposed,
    float* __restrict__ out_v) {
  int tid = threadIdx.x;
  int v = blockIdx.x * 256 + tid;
  bool active = v < kV;
  int vl = active ? v : (kV - 1);
  float w[kJ];
#pragma unroll
  for (int j = 0; j < kJ; ++j) w[j] = weights[(size_t)vl * kJ + j];
  int b0 = blockIdx.y * 8;
#pragma unroll 1
  for (int bi = 0; bi < 8; ++bi) {
    int b = b0 + bi;
    const float* Gb = Gskin + (size_t)b * 288;  // wave-uniform
    float T[12];
#pragma unroll
    for (int e = 0; e < 12; ++e) T[e] = 0.f;
#pragma unroll
    for (int j = 0; j < kJ; ++j) {
      float wj = w[j];
#pragma unroll
      for (int e = 0; e < 12; ++e) T[e] += wj * Gb[j * 12 + e];
    }
    float tr0 = trans[b * 3 + 0];
    float tr1 = trans[b * 3 + 1];
    float tr2 = trans[b * 3 + 2];
    size_t base = (size_t)b * kD + (size_t)vl * 3;
    float q0 = vposed[base + 0];
    float q1 = vposed[base + 1];
    float q2 = vposed[base + 2];
    if (active) {
      out_v[base + 0] = T[0] * q0 + T[1] * q1 + T[2] * q2 + T[3] + tr0;
      out_v[base + 1] = T[4] * q0 + T[5] * q1 + T[6] * q2 + T[7] + tr1;
      out_v[base + 2] = T[8] * q0 + T[9] * q1 + T[10] * q2 + T[11] + tr2;
    }
  }
}

// ---------------------------------------------------------------------------
extern "C" void kernel_launch(void* const* d_in, const int* in_sizes, int n_in,
                              void* d_out, int out_size, void* d_ws,
                              size_t ws_size, hipStream_t stream) {
  const float* pose       = (const float*)d_in[0];
  const float* betas      = (const float*)d_in[1];
  const float* trans      = (const float*)d_in[2];
  const float* v_template = (const float*)d_in[3];
  const float* shapedirs  = (const float*)d_in[4];
  const float* posedirs   = (const float*)d_in[5];
  const float* Jreg       = (const float*)d_in[6];
  const float* weights    = (const float*)d_in[7];

  float* out = (float*)d_out;
  float* out_v       = out;
  float* out_vposed  = out + (size_t)kB * kD;
  float* out_vshaped = out + 2 * (size_t)kB * kD;
  float* out_Jt      = out + 3 * (size_t)kB * kD;

  float* wsf   = (float*)d_ws;
  float* pfT   = wsf;                   // kNF*kB
  float* Gskin = pfT + kNF * kB;        // kB*288
  float* js    = Gskin + kB * 288;      // 72*10
  float* jt    = js + 72 * kNB;         // 72

  hipLaunchKernelGGL(kA_js, dim3(72), dim3(256), 0, stream, Jreg, shapedirs,
                     v_template, js, jt);
  hipLaunchKernelGGL(kC_batch, dim3(kB), dim3(64), 0, stream, pose, betas,
                     trans, js, jt, pfT, Gskin, out_Jt);
  hipLaunchKernelGGL(k14_fused, dim3((kD + 255) / 256, 16), dim3(256), 0,
                     stream, shapedirs, posedirs, v_template, betas, pfT,
                     out_vshaped, out_vposed);
  hipLaunchKernelGGL(k5_skin, dim3((kV + 255) / 256, 64), dim3(256), 0, stream,
                     weights, Gskin, trans, out_vposed, out_v);
}